// Round 2
// baseline (691.601 us; speedup 1.0000x reference)
//
#include <hip/hip_runtime.h>
#include <math.h>

// Problem constants
#define HID   4096
#define SLOTS 8
#define HEADS 8
#define BD    512
#define HD    64
#define BB    4
#define SS    4096
#define R64   64          // HEADS*SLOTS rows; r = h*8 + n
#define LSTR  72          // LDS row stride in bf16 elems (144 B)

typedef __attribute__((ext_vector_type(8))) short bf16x8;
typedef __attribute__((ext_vector_type(4))) float f32x4;

// fp32 -> bf16 bits, round-to-nearest-even (inputs finite)
__device__ __forceinline__ unsigned short f2bf(float x) {
  unsigned int u = __builtin_bit_cast(unsigned int, x);
  return (unsigned short)((u + 0x7fffu + ((u >> 16) & 1u)) >> 16);
}

// ---- 1: Q = ms @ Wq^T  (8x512). One wave per output element.
__global__ void q_kernel(const float* __restrict__ ms, const float* __restrict__ Wq,
                         float* __restrict__ Q) {
  int w = (blockIdx.x * blockDim.x + threadIdx.x) >> 6;
  int lane = threadIdx.x & 63;
  if (w >= SLOTS * BD) return;
  int n = w >> 9, o = w & (BD - 1);
  const float* a = ms + n * HID;
  const float* b = Wq + (size_t)o * HID;
  float acc = 0.f;
  for (int i = lane; i < HID; i += 64) acc = fmaf(a[i], b[i], acc);
  #pragma unroll
  for (int off = 32; off; off >>= 1) acc += __shfl_down(acc, off, 64);
  if (lane == 0) Q[w] = acc;
}

// ---- 2: QW[r][i] = 0.125 * sum_d Q[n][h*64+d] * Wk[h*64+d][i],  r = h*8+n  (bf16 out)
__global__ void qw_kernel(const float* __restrict__ Q, const float* __restrict__ Wk,
                          unsigned short* __restrict__ QW) {
  int idx = blockIdx.x * blockDim.x + threadIdx.x;   // 64*4096
  int r = idx >> 12, i = idx & (HID - 1);
  int h = r >> 3, n = r & 7;
  const float* q  = Q + n * BD + h * HD;
  const float* wk = Wk + (size_t)(h * HD) * HID + i;
  float acc = 0.f;
  #pragma unroll 8
  for (int d = 0; d < HD; ++d) acc = fmaf(q[d], wk[(size_t)d * HID], acc);
  QW[idx] = f2bf(acc * 0.125f);
}

// ---- 3: scores sp[b][r][s] = sum_k hs[b][s][k]*QW[r][k]  via bf16 MFMA.
// LDS-FREE: both operands fragment-loadable straight from global.
// grid (256 s-tiles of 16, 4 b), 256 thr. Tile M=16(s) x N=64(r), K=4096 full.
// Wave wv covers r = wv*16 + l16; A (hs rows) shared by the 4 waves via L1/L2.
// Layout (verified): A[m=l16][k=c*32+quad*8+j]; B[n=l16][k= same]; C col=l16(n), row=quad*4+reg(m).
__global__ __launch_bounds__(256) void scores_mfma(const float* __restrict__ hs,
                                                   const unsigned short* __restrict__ QW,
                                                   float* __restrict__ sp) {
  const int stile = blockIdx.x, b = blockIdx.y;
  const int tid = threadIdx.x;
  const int wv = tid >> 6, lane = tid & 63;
  const int quad = lane >> 4, l16 = lane & 15;
  const float* ap = hs + ((size_t)(b * SS + stile * 16 + l16)) * HID + quad * 8;
  const unsigned short* bp = QW + ((size_t)(wv * 16 + l16)) * HID + quad * 8;

  f32x4 acc = {};
  #pragma unroll 4
  for (int c = 0; c < 128; ++c) {
    float4 a0 = *(const float4*)(ap + (size_t)c * 32);
    float4 a1 = *(const float4*)(ap + (size_t)c * 32 + 4);
    bf16x8 bfrag = *(const bf16x8*)(bp + (size_t)c * 32);
    union { unsigned short us[8]; bf16x8 v; } ua;
    float f[8] = {a0.x, a0.y, a0.z, a0.w, a1.x, a1.y, a1.z, a1.w};
    #pragma unroll
    for (int j = 0; j < 8; ++j) ua.us[j] = f2bf(f[j]);
    acc = __builtin_amdgcn_mfma_f32_16x16x32_bf16(ua.v, bfrag, acc, 0, 0, 0);
  }
  // r = wv*16 + l16 (n/col), s = stile*16 + quad*4 + j (m/row)
  float4 v = make_float4(acc[0], acc[1], acc[2], acc[3]);
  *(float4*)(sp + ((size_t)(b * R64 + wv * 16 + l16)) * SS + stile * 16 + quad * 4) = v;
}

// ---- 4: softmax over s per (b,r), mask applied; bf16 attn out.
__global__ __launch_bounds__(256) void softmax_kernel(const float* __restrict__ sp,
                                                      const int* __restrict__ mask,
                                                      unsigned short* __restrict__ attn) {
  int br = blockIdx.x;            // b*64 + r
  int b = br >> 6;
  int tid = threadIdx.x;
  const float* row = sp + (size_t)br * SS;
  const int* mrow = mask + b * SS;
  float vals[16];
  float mx = -INFINITY;
  #pragma unroll
  for (int j = 0; j < 16; ++j) {
    int s = tid + j * 256;
    float v = row[s];
    if (mrow[s] == 0) v = -INFINITY;
    vals[j] = v;
    mx = fmaxf(mx, v);
  }
  __shared__ float redm[4], reds[4];
  #pragma unroll
  for (int off = 32; off; off >>= 1) mx = fmaxf(mx, __shfl_down(mx, off, 64));
  if ((tid & 63) == 0) redm[tid >> 6] = mx;
  __syncthreads();
  mx = fmaxf(fmaxf(redm[0], redm[1]), fmaxf(redm[2], redm[3]));
  float sum = 0.f;
  #pragma unroll
  for (int j = 0; j < 16; ++j) { vals[j] = expf(vals[j] - mx); sum += vals[j]; }
  #pragma unroll
  for (int off = 32; off; off >>= 1) sum += __shfl_down(sum, off, 64);
  if ((tid & 63) == 0) reds[tid >> 6] = sum;
  __syncthreads();
  sum = reds[0] + reds[1] + reds[2] + reds[3];
  float inv = 1.f / sum;
  #pragma unroll
  for (int j = 0; j < 16; ++j)
    attn[(size_t)br * SS + tid + j * 256] = f2bf(vals[j] * inv);
}

// ---- 5: ctx[b][r][i] = sum_s attn[b][r][s]*hs[b][s][i]  via bf16 MFMA.
// grid (256 i-tiles of 16, 4 b), 256 thr. Tile M=64(r) x N=16(i), K=4096(s) full.
// A (attn, bf16, L2-resident) loads straight from global; only the transposed hs
// slice needs LDS (16 x 64 per K-step, 2.3 KB). Depth-2 register prefetch.
__global__ __launch_bounds__(256) void ctx_mfma(const unsigned short* __restrict__ attn,
                                                const float* __restrict__ hs,
                                                float* __restrict__ ctx) {
  __shared__ unsigned short Bs[16 * LSTR];  // [i_local][s_local(64)]
  const int itile = blockIdx.x, b = blockIdx.y;
  const int tid = threadIdx.x;
  const int wv = tid >> 6, lane = tid & 63;
  const int quad = lane >> 4, l16 = lane & 15;
  // B staging: thread -> s-pair (2p,2p+1), i-pair (2g,2g+1)
  const int p = tid & 31, g = tid >> 5;
  const float* bbase = hs + ((size_t)(b * SS + 2 * p)) * HID + itile * 16 + 2 * g;
  // A fragments: wave wv covers r rows wv*16 + (m-index); lane reads row wv*16+l16
  const unsigned short* ap = attn + ((size_t)(b * R64 + wv * 16 + l16)) * SS + quad * 8;

  f32x4 acc = {};
  float2 hA0 = *(const float2*)(bbase);
  float2 hA1 = *(const float2*)(bbase + HID);
  float2 hB0 = *(const float2*)(bbase + (size_t)64 * HID);
  float2 hB1 = *(const float2*)(bbase + (size_t)64 * HID + HID);

  for (int cc = 0; cc < 64; cc += 2) {
    // ---- step A: c = cc
    __syncthreads();
    {
      unsigned int v0 = (unsigned int)f2bf(hA0.x) | ((unsigned int)f2bf(hA1.x) << 16);
      unsigned int v1 = (unsigned int)f2bf(hA0.y) | ((unsigned int)f2bf(hA1.y) << 16);
      ((unsigned int*)Bs)[(2 * g) * (LSTR / 2) + p]     = v0;   // Bs[2g][2p..2p+1]
      ((unsigned int*)Bs)[(2 * g + 1) * (LSTR / 2) + p] = v1;   // Bs[2g+1][2p..2p+1]
    }
    __syncthreads();
    if (cc + 2 < 64) {
      const float* bn = bbase + (size_t)(cc + 2) * 64 * HID;
      hA0 = *(const float2*)(bn);
      hA1 = *(const float2*)(bn + HID);
    }
    #pragma unroll
    for (int ks = 0; ks < 2; ++ks) {
      bf16x8 bfrag = *(const bf16x8*)&Bs[l16 * LSTR + ks * 32 + quad * 8];
      bf16x8 afrag = *(const bf16x8*)(ap + (size_t)cc * 64 + ks * 32);
      acc = __builtin_amdgcn_mfma_f32_16x16x32_bf16(afrag, bfrag, acc, 0, 0, 0);
    }
    // ---- step B: c = cc+1
    __syncthreads();
    {
      unsigned int v0 = (unsigned int)f2bf(hB0.x) | ((unsigned int)f2bf(hB1.x) << 16);
      unsigned int v1 = (unsigned int)f2bf(hB0.y) | ((unsigned int)f2bf(hB1.y) << 16);
      ((unsigned int*)Bs)[(2 * g) * (LSTR / 2) + p]     = v0;
      ((unsigned int*)Bs)[(2 * g + 1) * (LSTR / 2) + p] = v1;
    }
    __syncthreads();
    if (cc + 3 < 64) {
      const float* bn = bbase + (size_t)(cc + 3) * 64 * HID;
      hB0 = *(const float2*)(bn);
      hB1 = *(const float2*)(bn + HID);
    }
    #pragma unroll
    for (int ks = 0; ks < 2; ++ks) {
      bf16x8 bfrag = *(const bf16x8*)&Bs[l16 * LSTR + ks * 32 + quad * 8];
      bf16x8 afrag = *(const bf16x8*)(ap + (size_t)(cc + 1) * 64 + ks * 32);
      acc = __builtin_amdgcn_mfma_f32_16x16x32_bf16(afrag, bfrag, acc, 0, 0, 0);
    }
  }
  // D[m=r][n=i]: r = wv*16 + quad*4 + j, i = itile*16 + l16
  const int i = itile * 16 + l16;
  #pragma unroll
  for (int j = 0; j < 4; ++j)
    ctx[((size_t)(b * R64 + wv * 16 + quad * 4 + j)) * HID + i] = acc[j];
}

// ---- 6: out[b][n][hd] = sum_i ctx[b][h*8+n][i] * Wv[hd][i]
// One wave per (b,hd); loops all 8 n so Wv is streamed exactly once.
__global__ void out_kernel(const float* __restrict__ ctx, const float* __restrict__ Wv,
                           float* __restrict__ out) {
  int w = (blockIdx.x * blockDim.x + threadIdx.x) >> 6;   // 2048 = BB*BD waves
  int lane = threadIdx.x & 63;
  if (w >= BB * BD) return;
  int b = w >> 9, hd = w & 511, h = hd >> 6;
  const float* wvp = Wv + (size_t)hd * HID;
  const float* cb  = ctx + ((size_t)b * R64 + h * 8) * HID;  // 8 consecutive rows
  float acc[8] = {};
  for (int i = lane; i < HID; i += 64) {
    float wv = wvp[i];
    #pragma unroll
    for (int n = 0; n < 8; ++n) acc[n] = fmaf(cb[(size_t)n * HID + i], wv, acc[n]);
  }
  #pragma unroll
  for (int n = 0; n < 8; ++n) {
    float a = acc[n];
    #pragma unroll
    for (int off = 32; off; off >>= 1) a += __shfl_down(a, off, 64);
    if (lane == 0) out[((size_t)(b * SLOTS + n)) * BD + hd] = a;
  }
}

// ---- 7: y[bn][o] = sum_d out[bn][d] * Wo[o][d]
// One wave per o; loops all 32 bn so Wo is streamed exactly once; out is L1-resident.
__global__ void final_kernel(const float* __restrict__ out, const float* __restrict__ Wo,
                             float* __restrict__ y) {
  int w = (blockIdx.x * blockDim.x + threadIdx.x) >> 6;   // 4096 = HID waves
  int lane = threadIdx.x & 63;
  if (w >= HID) return;
  const float* wo = Wo + (size_t)w * BD;
  float wreg[8];
  #pragma unroll
  for (int j = 0; j < 8; ++j) wreg[j] = wo[lane + j * 64];
  for (int bn = 0; bn < BB * SLOTS; ++bn) {
    const float* orow = out + bn * BD;
    float acc = 0.f;
    #pragma unroll
    for (int j = 0; j < 8; ++j) acc = fmaf(orow[lane + j * 64], wreg[j], acc);
    #pragma unroll
    for (int off = 32; off; off >>= 1) acc += __shfl_down(acc, off, 64);
    if (lane == 0) y[(size_t)bn * HID + w] = acc;
  }
}

extern "C" void kernel_launch(void* const* d_in, const int* in_sizes, int n_in,
                              void* d_out, int out_size, void* d_ws, size_t ws_size,
                              hipStream_t stream) {
  const float* hs   = (const float*)d_in[0];
  const int*   mask = (const int*)d_in[1];
  const float* ms   = (const float*)d_in[2];
  const float* Wq   = (const float*)d_in[3];
  const float* Wk   = (const float*)d_in[4];
  const float* Wv   = (const float*)d_in[5];
  const float* Wo   = (const float*)d_in[6];

  // Workspace layout (~10.6 MB)
  char* ws = (char*)d_ws;
  float*          Q    = (float*)ws;          ws += 4096 * 4;                    // 16 KB
  unsigned short* QW   = (unsigned short*)ws; ws += R64 * HID * 2;               // 512 KB
  float*          sp   = (float*)ws;          ws += (size_t)BB * R64 * SS * 4;   // 4 MB
  unsigned short* attn = (unsigned short*)ws; ws += (size_t)BB * R64 * SS * 2;   // 2 MB
  float*          ctx  = (float*)ws;          ws += (size_t)BB * R64 * HID * 4;  // 4 MB
  float*          out  = (float*)ws;                                             // 64 KB

  q_kernel<<<dim3((SLOTS * BD * 64) / 256), 256, 0, stream>>>(ms, Wq, Q);
  qw_kernel<<<dim3((R64 * HID) / 256), 256, 0, stream>>>(Q, Wk, QW);
  scores_mfma<<<dim3(256, 4), 256, 0, stream>>>(hs, QW, sp);
  softmax_kernel<<<dim3(BB * R64), 256, 0, stream>>>(sp, mask, attn);
  ctx_mfma<<<dim3(256, 4), 256, 0, stream>>>(attn, hs, ctx);
  out_kernel<<<dim3((BB * BD * 64) / 256), 256, 0, stream>>>(ctx, Wv, out);
  final_kernel<<<dim3((HID * 64) / 256), 256, 0, stream>>>(out, Wo, (float*)d_out);
}

// Round 3
// 551.511 us; speedup vs baseline: 1.2540x; 1.2540x over previous
//
#include <hip/hip_runtime.h>
#include <math.h>

// Problem constants
#define HID   4096
#define SLOTS 8
#define HEADS 8
#define BD    512
#define HD    64
#define BB    4
#define SS    4096
#define R64   64          // HEADS*SLOTS rows; r = h*8 + n
#define LSTR  72          // padded LDS row stride (bf16 elems) for register-staged tiles
#define KC    1024        // K-chunk per block (K-split)
#define NKZ   4           // number of K chunks
#define NT    16          // K-steps per chunk (KC/64)

typedef __attribute__((ext_vector_type(8))) short bf16x8;
typedef __attribute__((ext_vector_type(4))) float f32x4;

// fp32 -> bf16 bits, round-to-nearest-even (inputs finite)
__device__ __forceinline__ unsigned short f2bf(float x) {
  unsigned int u = __builtin_bit_cast(unsigned int, x);
  return (unsigned short)((u + 0x7fffu + ((u >> 16) & 1u)) >> 16);
}

// async global->LDS, 16 bytes per lane (literal size per guide)
__device__ __forceinline__ void gl16(const void* g, void* l) {
  __builtin_amdgcn_global_load_lds(
      (const __attribute__((address_space(1))) unsigned int*)g,
      (__attribute__((address_space(3))) unsigned int*)l, 16, 0, 0);
}

// ---- 0: hsb = bf16(hs)  (read 256 MB, write 128 MB, pure stream)
__global__ __launch_bounds__(256) void hsb_kernel(const float* __restrict__ hs,
                                                  unsigned short* __restrict__ hsb) {
  const size_t total = (size_t)BB * SS * HID / 8;
  size_t stride = (size_t)gridDim.x * blockDim.x;
  for (size_t u = (size_t)blockIdx.x * blockDim.x + threadIdx.x; u < total; u += stride) {
    const float* src = hs + u * 8;
    float4 a = *(const float4*)src;
    float4 b = *(const float4*)(src + 4);
    union { unsigned short us[8]; uint4 q; } o;
    o.us[0] = f2bf(a.x); o.us[1] = f2bf(a.y); o.us[2] = f2bf(a.z); o.us[3] = f2bf(a.w);
    o.us[4] = f2bf(b.x); o.us[5] = f2bf(b.y); o.us[6] = f2bf(b.z); o.us[7] = f2bf(b.w);
    *(uint4*)(hsb + u * 8) = o.q;
  }
}

// ---- 1: Q = ms @ Wq^T  (8x512). One wave per output element.
__global__ void q_kernel(const float* __restrict__ ms, const float* __restrict__ Wq,
                         float* __restrict__ Q) {
  int w = (blockIdx.x * blockDim.x + threadIdx.x) >> 6;
  int lane = threadIdx.x & 63;
  if (w >= SLOTS * BD) return;
  int n = w >> 9, o = w & (BD - 1);
  const float* a = ms + n * HID;
  const float* b = Wq + (size_t)o * HID;
  float acc = 0.f;
  for (int i = lane; i < HID; i += 64) acc = fmaf(a[i], b[i], acc);
  #pragma unroll
  for (int off = 32; off; off >>= 1) acc += __shfl_down(acc, off, 64);
  if (lane == 0) Q[w] = acc;
}

// ---- 2: QW[r][i] = 0.125 * sum_d Q[n][h*64+d] * Wk[h*64+d][i],  r = h*8+n  (bf16 out)
__global__ void qw_kernel(const float* __restrict__ Q, const float* __restrict__ Wk,
                          unsigned short* __restrict__ QW) {
  int idx = blockIdx.x * blockDim.x + threadIdx.x;   // 64*4096
  int r = idx >> 12, i = idx & (HID - 1);
  int h = r >> 3, n = r & 7;
  const float* q  = Q + n * BD + h * HD;
  const float* wk = Wk + (size_t)(h * HD) * HID + i;
  float acc = 0.f;
  #pragma unroll 8
  for (int d = 0; d < HD; ++d) acc = fmaf(q[d], wk[(size_t)d * HID], acc);
  QW[idx] = f2bf(acc * 0.125f);
}

// ---- 3: partial scores sp[kz][b][r][s] = sum_{k chunk} hsb[b][s][k]*QW[r][k]  (bf16 MFMA)
// grid (64 s-tiles, 4 b, 4 kz), 256 thr. M=64(s) x N=64(r), K=1024.
// Both tiles staged via global_load_lds (linear LDS) with XOR swizzle:
//   lds_byte(row,kb) = row*128 + (kb ^ ((row&7)<<4)); global source pre-swizzled.
__global__ __launch_bounds__(256) void scores_mfma(const unsigned short* __restrict__ hsb,
                                                   const unsigned short* __restrict__ QW,
                                                   float* __restrict__ sp) {
  __shared__ __align__(16) unsigned short As[2][4096];  // [s(64)][k(64)] swizzled
  __shared__ __align__(16) unsigned short Bs[2][4096];  // [r(64)][k(64)] swizzled
  const int stile = blockIdx.x, b = blockIdx.y, kz = blockIdx.z;
  const int tid = threadIdx.x;
  const int wv = tid >> 6, lane = tid & 63;
  const int quad = lane >> 4, l16 = lane & 15;
  // staging map: issue i covers rows i*32+trow, 16B slot tslot (source-swizzled)
  const int trow = tid >> 3;                 // 0..31
  const int tslot = (tid & 7) << 4;          // byte slot 0..112
  const int scol = tslot ^ ((trow & 7) << 4);
  const char* aSrc0 = (const char*)hsb +
      (((size_t)(b * SS + stile * 64 + trow)) * HID + kz * KC) * 2 + scol;
  const char* aSrc1 = (const char*)hsb +
      (((size_t)(b * SS + stile * 64 + 32 + trow)) * HID + kz * KC) * 2 + scol;
  const char* bSrc0 = (const char*)QW + (((size_t)trow) * HID + kz * KC) * 2 + scol;
  const char* bSrc1 = (const char*)QW + (((size_t)(32 + trow)) * HID + kz * KC) * 2 + scol;

  f32x4 acc[4] = {};
  // prologue: stage step 0 into buf 0
  gl16(aSrc0, &As[0][tid * 8]);
  gl16(aSrc1, &As[0][2048 + tid * 8]);
  gl16(bSrc0, &Bs[0][tid * 8]);
  gl16(bSrc1, &Bs[0][2048 + tid * 8]);
  __syncthreads();

  const int sw = (l16 & 7) << 4;
  for (int c = 0; c < NT; ++c) {
    const int cur = c & 1, nxt = cur ^ 1;
    if (c < NT - 1) {
      const size_t off = (size_t)(c + 1) * 128;
      gl16(aSrc0 + off, &As[nxt][tid * 8]);
      gl16(aSrc1 + off, &As[nxt][2048 + tid * 8]);
      gl16(bSrc0 + off, &Bs[nxt][tid * 8]);
      gl16(bSrc1 + off, &Bs[nxt][2048 + tid * 8]);
    }
    const char* ab = (const char*)&As[cur][0];
    const char* bb = (const char*)&Bs[cur][0];
    #pragma unroll
    for (int ks = 0; ks < 2; ++ks) {
      bf16x8 bfrag = *(const bf16x8*)(bb + (wv * 16 + l16) * 128 + ((ks * 64 + quad * 16) ^ sw));
      #pragma unroll
      for (int mt = 0; mt < 4; ++mt) {
        bf16x8 afrag = *(const bf16x8*)(ab + (mt * 16 + l16) * 128 + ((ks * 64 + quad * 16) ^ sw));
        acc[mt] = __builtin_amdgcn_mfma_f32_16x16x32_bf16(afrag, bfrag, acc[mt], 0, 0, 0);
      }
    }
    __syncthreads();
  }
  const int r = wv * 16 + l16;
  #pragma unroll
  for (int mt = 0; mt < 4; ++mt) {
    int s = stile * 64 + mt * 16 + quad * 4;
    float4 v = make_float4(acc[mt][0], acc[mt][1], acc[mt][2], acc[mt][3]);
    *(float4*)(sp + ((size_t)((kz * BB + b) * R64 + r)) * SS + s) = v;
  }
}

// ---- 4: softmax over s per (b,r); sums the 4 K-partials, mask applied; bf16 attn out.
__global__ __launch_bounds__(256) void softmax_kernel(const float* __restrict__ sp,
                                                      const int* __restrict__ mask,
                                                      unsigned short* __restrict__ attn) {
  int br = blockIdx.x;            // b*64 + r
  int b = br >> 6;
  int tid = threadIdx.x;
  const float* p0 = sp + ((size_t)(0 * BB * R64) + br) * SS;
  const float* p1 = sp + ((size_t)(1 * BB * R64) + br) * SS;
  const float* p2 = sp + ((size_t)(2 * BB * R64) + br) * SS;
  const float* p3 = sp + ((size_t)(3 * BB * R64) + br) * SS;
  const int* mrow = mask + b * SS;
  float vals[16];
  float mx = -INFINITY;
  #pragma unroll
  for (int j = 0; j < 16; ++j) {
    int s = tid + j * 256;
    float v = p0[s] + p1[s] + p2[s] + p3[s];
    if (mrow[s] == 0) v = -INFINITY;
    vals[j] = v;
    mx = fmaxf(mx, v);
  }
  __shared__ float redm[4], reds[4];
  #pragma unroll
  for (int off = 32; off; off >>= 1) mx = fmaxf(mx, __shfl_down(mx, off, 64));
  if ((tid & 63) == 0) redm[tid >> 6] = mx;
  __syncthreads();
  mx = fmaxf(fmaxf(redm[0], redm[1]), fmaxf(redm[2], redm[3]));
  float sum = 0.f;
  #pragma unroll
  for (int j = 0; j < 16; ++j) { vals[j] = expf(vals[j] - mx); sum += vals[j]; }
  #pragma unroll
  for (int off = 32; off; off >>= 1) sum += __shfl_down(sum, off, 64);
  if ((tid & 63) == 0) reds[tid >> 6] = sum;
  __syncthreads();
  sum = reds[0] + reds[1] + reds[2] + reds[3];
  float inv = 1.f / sum;
  #pragma unroll
  for (int j = 0; j < 16; ++j)
    attn[(size_t)br * SS + tid + j * 256] = f2bf(vals[j] * inv);
}

// ---- 5: partial ctx[kz][b][r][i] = sum_{s chunk} attn[b][r][s]*hsb[b][s][i]  (bf16 MFMA)
// grid (64 i-tiles, 4 b, 4 kz). M=64(r) x N=64(i), K=1024(s).
// A (attn) staged via global_load_lds (swizzled linear); B (hs^T) register-transposed
// into padded LDS (LSTR=72) with depth-2 prefetch.
__global__ __launch_bounds__(256) void ctx_mfma(const unsigned short* __restrict__ attn,
                                                const unsigned short* __restrict__ hsb,
                                                float* __restrict__ ctxp) {
  __shared__ __align__(16) unsigned short As[2][4096];      // [r(64)][s(64)] swizzled
  __shared__ __align__(16) unsigned short Bs[2][64 * LSTR]; // [i(64)][s(64)] padded
  const int itile = blockIdx.x, b = blockIdx.y, kz = blockIdx.z;
  const int tid = threadIdx.x;
  const int wv = tid >> 6, lane = tid & 63;
  const int quad = lane >> 4, l16 = lane & 15;
  // A staging (global_load_lds)
  const int trow = tid >> 3;
  const int tslot = (tid & 7) << 4;
  const int scol = tslot ^ ((trow & 7) << 4);
  const char* aSrc0 = (const char*)attn +
      (((size_t)(b * R64 + trow)) * SS + kz * KC) * 2 + scol;
  const char* aSrc1 = (const char*)attn +
      (((size_t)(b * R64 + 32 + trow)) * SS + kz * KC) * 2 + scol;
  // B staging: thread -> s-pair p (rows 2p,2p+1), i-group g (8 cols)
  const int p = tid & 31, g = tid >> 5;
  const unsigned short* hb = hsb + ((size_t)(b * SS + kz * KC + 2 * p)) * HID + itile * 64 + g * 8;

  f32x4 acc[4] = {};
  // prologue: step 0 into buf 0
  uint4 h0 = *(const uint4*)(hb);
  uint4 h1 = *(const uint4*)(hb + HID);
  gl16(aSrc0, &As[0][tid * 8]);
  gl16(aSrc1, &As[0][2048 + tid * 8]);
  {
    const unsigned short* u0 = (const unsigned short*)&h0;
    const unsigned short* u1 = (const unsigned short*)&h1;
    unsigned int* bs32 = (unsigned int*)&Bs[0][0];
    #pragma unroll
    for (int j = 0; j < 8; ++j)
      bs32[(g * 8 + j) * (LSTR / 2) + p] = (unsigned int)u0[j] | ((unsigned int)u1[j] << 16);
  }
  h0 = *(const uint4*)(hb + (size_t)64 * HID);
  h1 = *(const uint4*)(hb + (size_t)65 * HID);
  __syncthreads();

  const int sw = (l16 & 7) << 4;
  for (int c = 0; c < NT; ++c) {
    const int cur = c & 1, nxt = cur ^ 1;
    if (c < NT - 1) {
      const size_t off = (size_t)(c + 1) * 128;
      gl16(aSrc0 + off, &As[nxt][tid * 8]);
      gl16(aSrc1 + off, &As[nxt][2048 + tid * 8]);
      const unsigned short* u0 = (const unsigned short*)&h0;
      const unsigned short* u1 = (const unsigned short*)&h1;
      unsigned int* bs32 = (unsigned int*)&Bs[nxt][0];
      #pragma unroll
      for (int j = 0; j < 8; ++j)
        bs32[(g * 8 + j) * (LSTR / 2) + p] = (unsigned int)u0[j] | ((unsigned int)u1[j] << 16);
      if (c < NT - 2) {
        const unsigned short* hn = hb + (size_t)(c + 2) * 64 * HID;
        h0 = *(const uint4*)(hn);
        h1 = *(const uint4*)(hn + HID);
      }
    }
    const char* ab = (const char*)&As[cur][0];
    #pragma unroll
    for (int ks = 0; ks < 2; ++ks) {
      bf16x8 bfrag = *(const bf16x8*)&Bs[cur][(wv * 16 + l16) * LSTR + ks * 32 + quad * 8];
      #pragma unroll
      for (int mt = 0; mt < 4; ++mt) {
        bf16x8 afrag = *(const bf16x8*)(ab + (mt * 16 + l16) * 128 + ((ks * 64 + quad * 16) ^ sw));
        acc[mt] = __builtin_amdgcn_mfma_f32_16x16x32_bf16(afrag, bfrag, acc[mt], 0, 0, 0);
      }
    }
    __syncthreads();
  }
  const int i = itile * 64 + wv * 16 + l16;
  #pragma unroll
  for (int mt = 0; mt < 4; ++mt) {
    int r0 = mt * 16 + quad * 4;
    #pragma unroll
    for (int j = 0; j < 4; ++j)
      ctxp[((size_t)((kz * BB + b) * R64 + r0 + j)) * HID + i] = acc[mt][j];
  }
}

// ---- 5b: fold the 4 K-partials of ctx into one buffer (float4 streaming)
__global__ void ctxsum_kernel(const float* __restrict__ ctxp, float* __restrict__ ctxs) {
  int idx = blockIdx.x * blockDim.x + threadIdx.x;   // 262144 float4s
  const size_t n4 = (size_t)BB * R64 * HID / 4;      // elems/4 per partial
  if ((size_t)idx >= n4) return;
  const float4* a = (const float4*)ctxp;
  float4 v0 = a[idx];
  float4 v1 = a[idx + n4];
  float4 v2 = a[idx + 2 * n4];
  float4 v3 = a[idx + 3 * n4];
  float4 r = make_float4(v0.x + v1.x + v2.x + v3.x, v0.y + v1.y + v2.y + v3.y,
                         v0.z + v1.z + v2.z + v3.z, v0.w + v1.w + v2.w + v3.w);
  ((float4*)ctxs)[idx] = r;
}

// ---- 6: out[b][n][hd] = sum_i ctx[b][h*8+n][i] * Wv[hd][i]
__global__ void out_kernel(const float* __restrict__ ctx, const float* __restrict__ Wv,
                           float* __restrict__ out) {
  int w = (blockIdx.x * blockDim.x + threadIdx.x) >> 6;   // 2048 = BB*BD waves
  int lane = threadIdx.x & 63;
  if (w >= BB * BD) return;
  int b = w >> 9, hd = w & 511, h = hd >> 6;
  const float* wvp = Wv + (size_t)hd * HID;
  const float* cb  = ctx + ((size_t)b * R64 + h * 8) * HID;  // 8 consecutive rows
  float acc[8] = {};
  for (int i = lane; i < HID; i += 64) {
    float wv = wvp[i];
    #pragma unroll
    for (int n = 0; n < 8; ++n) acc[n] = fmaf(cb[(size_t)n * HID + i], wv, acc[n]);
  }
  #pragma unroll
  for (int n = 0; n < 8; ++n) {
    float a = acc[n];
    #pragma unroll
    for (int off = 32; off; off >>= 1) a += __shfl_down(a, off, 64);
    if (lane == 0) out[((size_t)(b * SLOTS + n)) * BD + hd] = a;
  }
}

// ---- 7: y[bn][o] = sum_d out[bn][d] * Wo[o][d]
__global__ void final_kernel(const float* __restrict__ out, const float* __restrict__ Wo,
                             float* __restrict__ y) {
  int w = (blockIdx.x * blockDim.x + threadIdx.x) >> 6;   // 4096 = HID waves
  int lane = threadIdx.x & 63;
  if (w >= HID) return;
  const float* wo = Wo + (size_t)w * BD;
  float wreg[8];
  #pragma unroll
  for (int j = 0; j < 8; ++j) wreg[j] = wo[lane + j * 64];
  for (int bn = 0; bn < BB * SLOTS; ++bn) {
    const float* orow = out + bn * BD;
    float acc = 0.f;
    #pragma unroll
    for (int j = 0; j < 8; ++j) acc = fmaf(orow[lane + j * 64], wreg[j], acc);
    #pragma unroll
    for (int off = 32; off; off >>= 1) acc += __shfl_down(acc, off, 64);
    if (lane == 0) y[(size_t)bn * HID + w] = acc;
  }
}

extern "C" void kernel_launch(void* const* d_in, const int* in_sizes, int n_in,
                              void* d_out, int out_size, void* d_ws, size_t ws_size,
                              hipStream_t stream) {
  const float* hs   = (const float*)d_in[0];
  const int*   mask = (const int*)d_in[1];
  const float* ms   = (const float*)d_in[2];
  const float* Wq   = (const float*)d_in[3];
  const float* Wk   = (const float*)d_in[4];
  const float* Wv   = (const float*)d_in[5];
  const float* Wo   = (const float*)d_in[6];

  // Workspace layout (~167 MB)
  char* ws = (char*)d_ws;
  float*          Q    = (float*)ws;          ws += 4096 * 4;                          // 16 KB
  unsigned short* QW   = (unsigned short*)ws; ws += R64 * HID * 2;                     // 512 KB
  unsigned short* hsb  = (unsigned short*)ws; ws += (size_t)BB * SS * HID * 2;         // 128 MB
  float*          sp   = (float*)ws;          ws += (size_t)NKZ * BB * R64 * SS * 4;   // 16 MB
  unsigned short* attn = (unsigned short*)ws; ws += (size_t)BB * R64 * SS * 2;         // 2 MB
  float*          ctxp = (float*)ws;          ws += (size_t)NKZ * BB * R64 * HID * 4;  // 16 MB
  float*          ctxs = (float*)ws;          ws += (size_t)BB * R64 * HID * 4;        // 4 MB
  float*          out  = (float*)ws;                                                   // 64 KB

  hsb_kernel<<<dim3(2048), 256, 0, stream>>>(hs, hsb);
  q_kernel<<<dim3((SLOTS * BD * 64) / 256), 256, 0, stream>>>(ms, Wq, Q);
  qw_kernel<<<dim3((R64 * HID) / 256), 256, 0, stream>>>(Q, Wk, QW);
  scores_mfma<<<dim3(64, 4, 4), 256, 0, stream>>>(hsb, QW, sp);
  softmax_kernel<<<dim3(BB * R64), 256, 0, stream>>>(sp, mask, attn);
  ctx_mfma<<<dim3(64, 4, 4), 256, 0, stream>>>(attn, hsb, ctxp);
  ctxsum_kernel<<<dim3((BB * R64 * HID / 4) / 256), 256, 0, stream>>>(ctxp, ctxs);
  out_kernel<<<dim3((BB * BD * 64) / 256), 256, 0, stream>>>(ctxs, Wv, out);
  final_kernel<<<dim3((HID * 64) / 256), 256, 0, stream>>>(out, Wo, (float*)d_out);
}